// Round 13
// baseline (643.142 us; speedup 1.0000x reference)
//
#include <hip/hip_runtime.h>
#include <math.h>

#define N_PTS 16384
#define KNN   16
#define NCLS  20
#define BND_W 1.0f

#define G       32
#define NBINS   (G * G * G)          // 32768
#define CELL_H  0.28125f             // 9/32, exact in binary
#define GRID_LO -4.5f
#define INV_H   (32.0f / 9.0f)

// identical distance expression everywhere (forced fmaf -> bit-identical)
__device__ __forceinline__ float dist2f(float ax, float ay, float az,
                                        float bx, float by, float bz) {
    float dx = ax - bx, dy = ay - by, dz = az - bz;
    return __builtin_fmaf(dx, dx, __builtin_fmaf(dy, dy, dz * dz));
}

__device__ __forceinline__ int clampi(int v, int lo, int hi) {
    return min(hi, max(lo, v));
}

__device__ __forceinline__ void cell_xyz(float x, float y, float z,
                                         int& cx, int& cy, int& cz) {
    cx = clampi((int)floorf((x - GRID_LO) * INV_H), 0, G - 1);
    cy = clampi((int)floorf((y - GRID_LO) * INV_H), 0, G - 1);
    cz = clampi((int)floorf((z - GRID_LO) * INV_H), 0, G - 1);
}

__global__ __launch_bounds__(256) void k_hist(const float* __restrict__ coord,
                                              int* __restrict__ hist) {
    const int i = blockIdx.x * 256 + threadIdx.x;
    int cx, cy, cz;
    cell_xyz(coord[3 * i], coord[3 * i + 1], coord[3 * i + 2], cx, cy, cz);
    atomicAdd(&hist[(cx * G + cy) * G + cz], 1);
}

// single block, 512 threads, 64 bins each: exclusive scan -> bin_start, cursor
__global__ __launch_bounds__(512) void k_scan(const int* __restrict__ hist,
                                              int* __restrict__ bin_start,
                                              int* __restrict__ cursor) {
    __shared__ int part[512];
    const int t = threadIdx.x;
    const int base = t * 64;
    int s = 0;
#pragma unroll
    for (int k = 0; k < 64; k++) s += hist[base + k];
    part[t] = s;
    __syncthreads();
    // Hillis-Steele inclusive scan
    for (int off = 1; off < 512; off <<= 1) {
        int v = (t >= off) ? part[t - off] : 0;
        __syncthreads();
        part[t] += v;
        __syncthreads();
    }
    int run = part[t] - s;   // exclusive base for this thread's chunk
#pragma unroll
    for (int k = 0; k < 64; k++) {
        bin_start[base + k] = run;
        cursor[base + k] = run;
        run += hist[base + k];
    }
    if (t == 511) bin_start[NBINS] = run;   // == N_PTS
}

// scatter into sorted order; record = (x,y,z, pack(orig<<5 | lab+1))
__global__ __launch_bounds__(256) void k_scatter(const float* __restrict__ coord,
                                                 const int* __restrict__ seg,
                                                 int* __restrict__ cursor,
                                                 float4* __restrict__ pos) {
    const int i = blockIdx.x * 256 + threadIdx.x;
    float x = coord[3 * i], y = coord[3 * i + 1], z = coord[3 * i + 2];
    int cx, cy, cz;
    cell_xyz(x, y, z, cx, cy, cz);
    int idx = atomicAdd(&cursor[(cx * G + cy) * G + cz], 1);
    float4 rec;
    rec.x = x; rec.y = y; rec.z = z;
    rec.w = __int_as_float((i << 5) | ((seg[i] + 1) & 31));
    pos[idx] = rec;
}

__device__ __forceinline__ float waveReduceSum(float v) {
#pragma unroll
    for (int off = 32; off > 0; off >>= 1) v += __shfl_down(v, off, 64);
    return v;
}

// 8 lanes per sorted point. Phase A: expanding shells for exact dmin_diff^2.
// Phase B: exact count of d^2 < dmin_diff^2 over a guaranteed-covering cube.
// Then fused CE + final scalar (done-counter).
__global__ __launch_bounds__(256) void k_search(const float4* __restrict__ pos,
                                                const int* __restrict__ bs,
                                                const float* __restrict__ logits,
                                                float* __restrict__ accum,
                                                unsigned* __restrict__ done,
                                                float* __restrict__ out) {
    const int gid = blockIdx.x * 256 + threadIdx.x;
    const int g   = gid >> 3;      // sorted point id
    const int sub = gid & 7;
    const float4 me = pos[g];
    const int bits  = __float_as_int(me.w);
    const int labp1 = bits & 31;
    const int orig  = bits >> 5;
    int cx, cy, cz;
    cell_xyz(me.x, me.y, me.z, cx, cy, cz);

    // ---- Phase A: min d^2 over valid, diff-labeled points ----
    float db2 = 3.0e38f;
    for (int r = 1;; r++) {
        const int x0 = max(0, cx - r), x1 = min(G - 1, cx + r);
        const int y0 = max(0, cy - r), y1 = min(G - 1, cy + r);
        const int z0 = max(0, cz - r), z1 = min(G - 1, cz + r);
        for (int ix = x0; ix <= x1; ix++) {
            for (int iy = y0; iy <= y1; iy++) {
                const int mxy = max(abs(ix - cx), abs(iy - cy));
                for (int iz = z0; iz <= z1; iz++) {
                    if (r > 1 && max(mxy, abs(iz - cz)) < r) continue;  // shell only
                    const int c = (ix * G + iy) * G + iz;
                    const int s = bs[c], e = bs[c + 1];
                    for (int j = s + sub; j < e; j += 8) {
                        float4 p = pos[j];
                        float d2 = dist2f(me.x, me.y, me.z, p.x, p.y, p.z);
                        int pl = __float_as_int(p.w) & 31;
                        bool diff = (pl != 0) && (pl != labp1);
                        db2 = fminf(db2, diff ? d2 : 3.0e38f);
                    }
                }
            }
        }
#pragma unroll
        for (int m = 1; m < 8; m <<= 1) db2 = fminf(db2, __shfl_xor(db2, m, 64));
        float rh = (float)r * CELL_H;
        if (db2 <= rh * rh || r >= G - 1) break;
    }

    // ---- Phase B: count d^2 strictly below db2 (exact covering cube) ----
    int S = 1;
    while (S < G - 1) {
        float sh = (float)S * CELL_H;
        if (sh * sh >= db2) break;   // points outside cube S have d^2 >= (S*h)^2 >= db2
        S++;
    }
    int cnt = 0;
    {
        const int x0 = max(0, cx - S), x1 = min(G - 1, cx + S);
        const int y0 = max(0, cy - S), y1 = min(G - 1, cy + S);
        const int z0 = max(0, cz - S), z1 = min(G - 1, cz + S);
        for (int ix = x0; ix <= x1; ix++)
            for (int iy = y0; iy <= y1; iy++)
                for (int iz = z0; iz <= z1; iz++) {
                    const int c = (ix * G + iy) * G + iz;
                    const int s = bs[c], e = bs[c + 1];
                    for (int j = s + sub; j < e; j += 8) {
                        float4 p = pos[j];
                        float d2 = dist2f(me.x, me.y, me.z, p.x, p.y, p.z);
                        cnt += (d2 < db2) ? 1 : 0;   // argmin point: d2==db2 -> excluded
                    }
                }
    }
#pragma unroll
    for (int m = 1; m < 8; m <<= 1) cnt += __shfl_xor(cnt, m, 64);

    // ---- CE (one lane per point) ----
    float sm = 0.f, nm = 0.f, sb = 0.f, nb = 0.f;
    if (sub == 0) {
        bool valid = (labp1 != 0);
        const float4* row4 = (const float4*)(logits + (size_t)orig * NCLS);
        float a[NCLS];
        float4 v0 = row4[0], v1 = row4[1], v2 = row4[2], v3 = row4[3], v4 = row4[4];
        a[0]=v0.x; a[1]=v0.y; a[2]=v0.z; a[3]=v0.w;
        a[4]=v1.x; a[5]=v1.y; a[6]=v1.z; a[7]=v1.w;
        a[8]=v2.x; a[9]=v2.y; a[10]=v2.z; a[11]=v2.w;
        a[12]=v3.x; a[13]=v3.y; a[14]=v3.z; a[15]=v3.w;
        a[16]=v4.x; a[17]=v4.y; a[18]=v4.z; a[19]=v4.w;
        float mx = a[0];
#pragma unroll
        for (int c = 1; c < NCLS; c++) mx = fmaxf(mx, a[c]);
        float se = 0.f;
#pragma unroll
        for (int c = 0; c < NCLS; c++) se += __expf(a[c] - mx);
        int lab = labp1 - 1;
        int tgt = min(max(lab, 0), NCLS - 1);
        float at = 0.f;
#pragma unroll
        for (int c = 0; c < NCLS; c++) at += (c == tgt) ? a[c] : 0.f;
        float logp = at - mx - __logf(se);
        // cnt includes self once; boundary iff rank of nearest-diff < K
        bool bnd = valid && ((cnt - 1) < KNN);
        if (valid) { sm = logp; nm = 1.f; }
        if (bnd)   { sb = logp; nb = 1.f; }
    }
    sm = waveReduceSum(sm);
    nm = waveReduceSum(nm);
    sb = waveReduceSum(sb);
    nb = waveReduceSum(nb);
    if ((threadIdx.x & 63) == 0) {
        atomicAdd(&accum[0], sm);
        atomicAdd(&accum[1], nm);
        atomicAdd(&accum[2], sb);
        atomicAdd(&accum[3], nb);
    }
    __syncthreads();
    if (threadIdx.x == 0) {
        __threadfence();
        if (atomicAdd(done, 1u) == (unsigned)(gridDim.x - 1)) {
            float Sm = atomicAdd(&accum[0], 0.f);
            float Cm = atomicAdd(&accum[1], 0.f);
            float Sb = atomicAdd(&accum[2], 0.f);
            float Cb = atomicAdd(&accum[3], 0.f);
            float main_loss = (Cm > 0.f) ? (-Sm / fmaxf(Cm, 1.f)) : 0.f;
            float bnd_loss  = (Cb > 0.f) ? (-Sb / fmaxf(Cb, 1.f)) : 0.f;
            out[0] = main_loss + BND_W * bnd_loss;
        }
    }
}

extern "C" void kernel_launch(void* const* d_in, const int* in_sizes, int n_in,
                              void* d_out, int out_size, void* d_ws, size_t ws_size,
                              hipStream_t stream) {
    const float* coord  = (const float*)d_in[0];
    const float* logits = (const float*)d_in[1];
    const int*   seg    = (const int*)d_in[2];
    (void)in_sizes; (void)n_in; (void)out_size; (void)ws_size;

    char* w = (char*)d_ws;
    int*      hist      = (int*)(w + 0x00000);          // 32768 i32 (128 KB)
    int*      bin_start = (int*)(w + 0x40000);          // 32769 i32
    int*      cursor    = (int*)(w + 0x60000);          // 32768 i32
    float4*   pos       = (float4*)(w + 0x80000);       // 16384 f32x4 (256 KB)
    float*    accum     = (float*)(w + 0xC0000);        // 4 f32
    unsigned* done      = (unsigned*)(w + 0xC0000 + 16);

    hipMemsetAsync(hist, 0, NBINS * sizeof(int), stream);
    hipMemsetAsync(accum, 0, 32, stream);

    k_hist   <<<N_PTS / 256, 256, 0, stream>>>(coord, hist);
    k_scan   <<<1, 512, 0, stream>>>(hist, bin_start, cursor);
    k_scatter<<<N_PTS / 256, 256, 0, stream>>>(coord, seg, cursor, pos);
    k_search <<<(N_PTS * 8) / 256, 256, 0, stream>>>(pos, bin_start, logits,
                                                     accum, done, (float*)d_out);
}

// Round 14
// 196.622 us; speedup vs baseline: 3.2710x; 3.2710x over previous
//
#include <hip/hip_runtime.h>
#include <math.h>

#define N_PTS 16384
#define KNN   16
#define NCLS  20
#define BND_W 1.0f

#define G       32
#define NBINS   (G * G * G)          // 32768
#define CELL_H  0.28125f             // 9/32, exact in binary
#define H2      0.0791015625f        // (9/32)^2, exact
#define GRID_LO -4.5f
#define INV_H   (32.0f / 9.0f)

// identical distance expression everywhere (forced fmaf -> bit-identical)
__device__ __forceinline__ float dist2f(float ax, float ay, float az,
                                        float bx, float by, float bz) {
    float dx = ax - bx, dy = ay - by, dz = az - bz;
    return __builtin_fmaf(dx, dx, __builtin_fmaf(dy, dy, dz * dz));
}

__device__ __forceinline__ int clampi(int v, int lo, int hi) {
    return min(hi, max(lo, v));
}

__device__ __forceinline__ void cell_xyz(float x, float y, float z,
                                         int& cx, int& cy, int& cz) {
    cx = clampi((int)floorf((x - GRID_LO) * INV_H), 0, G - 1);
    cy = clampi((int)floorf((y - GRID_LO) * INV_H), 0, G - 1);
    cz = clampi((int)floorf((z - GRID_LO) * INV_H), 0, G - 1);
}

__device__ __forceinline__ float waveReduceSum(float v) {
#pragma unroll
    for (int off = 32; off > 0; off >>= 1) v += __shfl_down(v, off, 64);
    return v;
}

// hist + fused main-CE (coalesced logits pass); logp stored for later gather
__global__ __launch_bounds__(256) void k_prep(const float* __restrict__ coord,
                                              const int* __restrict__ seg,
                                              const float* __restrict__ logits,
                                              int* __restrict__ hist,
                                              float* __restrict__ logp,
                                              float* __restrict__ accum) {
    const int i = blockIdx.x * 256 + threadIdx.x;
    int cx, cy, cz;
    cell_xyz(coord[3 * i], coord[3 * i + 1], coord[3 * i + 2], cx, cy, cz);
    atomicAdd(&hist[(cx * G + cy) * G + cz], 1);

    int sg = seg[i];
    bool valid = (sg != -1);
    const float4* row4 = (const float4*)(logits + (size_t)i * NCLS);
    float a[NCLS];
    float4 v0 = row4[0], v1 = row4[1], v2 = row4[2], v3 = row4[3], v4 = row4[4];
    a[0]=v0.x; a[1]=v0.y; a[2]=v0.z; a[3]=v0.w;
    a[4]=v1.x; a[5]=v1.y; a[6]=v1.z; a[7]=v1.w;
    a[8]=v2.x; a[9]=v2.y; a[10]=v2.z; a[11]=v2.w;
    a[12]=v3.x; a[13]=v3.y; a[14]=v3.z; a[15]=v3.w;
    a[16]=v4.x; a[17]=v4.y; a[18]=v4.z; a[19]=v4.w;
    float mx = a[0];
#pragma unroll
    for (int c = 1; c < NCLS; c++) mx = fmaxf(mx, a[c]);
    float se = 0.f;
#pragma unroll
    for (int c = 0; c < NCLS; c++) se += __expf(a[c] - mx);
    int tgt = min(max(sg, 0), NCLS - 1);
    float at = 0.f;
#pragma unroll
    for (int c = 0; c < NCLS; c++) at += (c == tgt) ? a[c] : 0.f;
    float lp = at - mx - __logf(se);
    logp[i] = lp;

    float sm = valid ? lp : 0.f, nm = valid ? 1.f : 0.f;
    sm = waveReduceSum(sm);
    nm = waveReduceSum(nm);
    if ((threadIdx.x & 63) == 0) {
        atomicAdd(&accum[0], sm);
        atomicAdd(&accum[1], nm);
    }
}

// single block; int4-vectorized chunk sums + LDS Hillis-Steele
__global__ __launch_bounds__(512) void k_scan(const int4* __restrict__ h4,
                                              int* __restrict__ bin_start,
                                              int* __restrict__ cursor) {
    __shared__ int part[512];
    const int t = threadIdx.x;
    int4 v[16];
    int s = 0;
#pragma unroll
    for (int k = 0; k < 16; k++) {
        v[k] = h4[t * 16 + k];
        s += v[k].x + v[k].y + v[k].z + v[k].w;
    }
    part[t] = s;
    __syncthreads();
    for (int off = 1; off < 512; off <<= 1) {
        int u = (t >= off) ? part[t - off] : 0;
        __syncthreads();
        part[t] += u;
        __syncthreads();
    }
    int run = part[t] - s;   // exclusive base of this thread's 64-bin chunk
    int4* bs4 = (int4*)bin_start;
    int4* cu4 = (int4*)cursor;
#pragma unroll
    for (int k = 0; k < 16; k++) {
        int4 w;
        w.x = run;
        w.y = w.x + v[k].x;
        w.z = w.y + v[k].y;
        w.w = w.z + v[k].z;
        run = w.w + v[k].w;
        bs4[t * 16 + k] = w;
        cu4[t * 16 + k] = w;
    }
    if (t == 511) bin_start[NBINS] = run;   // == N_PTS
}

// scatter into sorted order; record = (x,y,z, pack(orig<<5 | lab+1))
__global__ __launch_bounds__(256) void k_scatter(const float* __restrict__ coord,
                                                 const int* __restrict__ seg,
                                                 int* __restrict__ cursor,
                                                 float4* __restrict__ pos) {
    const int i = blockIdx.x * 256 + threadIdx.x;
    float x = coord[3 * i], y = coord[3 * i + 1], z = coord[3 * i + 2];
    int cx, cy, cz;
    cell_xyz(x, y, z, cx, cy, cz);
    int idx = atomicAdd(&cursor[(cx * G + cy) * G + cz], 1);
    float4 rec;
    rec.x = x; rec.y = y; rec.z = z;
    rec.w = __int_as_float((i << 5) | ((seg[i] + 1) & 31));
    pos[idx] = rec;
}

// One lane per sorted point. r=1 cube as 9 register-cached z-runs.
// Converged (db2 <= h^2: cube-1 provably covers min AND count) -> finish here.
// Else push to queue for the brute-force kernel.
__global__ __launch_bounds__(64) void k_search(const float4* __restrict__ pos,
                                               const int* __restrict__ bs,
                                               const float* __restrict__ logp,
                                               float* __restrict__ accum,
                                               int* __restrict__ queue,
                                               int* __restrict__ qcount) {
    const int i = blockIdx.x * 64 + threadIdx.x;
    const float4 me = pos[i];
    const int bits  = __float_as_int(me.w);
    const int labp1 = bits & 31;
    const int orig  = bits >> 5;
    int cx, cy, cz;
    cell_xyz(me.x, me.y, me.z, cx, cy, cz);
    const int zlo = max(0, cz - 1), zhi = min(G - 1, cz + 1);

    int lo[9], hi[9];
#pragma unroll
    for (int dx = 0; dx < 3; dx++)
#pragma unroll
        for (int dy = 0; dy < 3; dy++) {
            const int q = dx * 3 + dy;
            int ix = cx + dx - 1, iy = cy + dy - 1;
            bool ok = (ix >= 0) && (ix < G) && (iy >= 0) && (iy < G);
            int cb = (ix * G + iy) * G;
            lo[q] = ok ? bs[cb + zlo] : 0;
            hi[q] = ok ? bs[cb + zhi + 1] : 0;
        }

    // Phase A over the 27-cell cube (9 z-runs)
    float db2 = 3.0e38f;
#pragma unroll
    for (int q = 0; q < 9; q++)
        for (int j = lo[q]; j < hi[q]; j++) {
            float4 p = pos[j];
            float d2 = dist2f(me.x, me.y, me.z, p.x, p.y, p.z);
            int pl = __float_as_int(p.w) & 31;
            bool diff = (pl != 0) && (pl != labp1);
            db2 = fminf(db2, diff ? d2 : 3.0e38f);
        }

    float sb = 0.f, nb = 0.f;
    if (db2 <= H2) {
        // Phase B: count d2 < db2; all qualifying points are inside cube-1
        int cnt = 0;
#pragma unroll
        for (int q = 0; q < 9; q++)
            for (int j = lo[q]; j < hi[q]; j++) {
                float4 p = pos[j];
                float d2 = dist2f(me.x, me.y, me.z, p.x, p.y, p.z);
                cnt += (d2 < db2) ? 1 : 0;   // self once; argmin excluded (d2==db2)
            }
        bool bnd = (labp1 != 0) && ((cnt - 1) < KNN);
        if (bnd) { sb = logp[orig]; nb = 1.f; }
    } else {
        int qi = atomicAdd(qcount, 1);
        queue[qi] = i;
    }
    sb = waveReduceSum(sb);
    nb = waveReduceSum(nb);
    if (threadIdx.x == 0 && nb > 0.f) {
        atomicAdd(&accum[2], sb);
        atomicAdd(&accum[3], nb);
    }
}

// Brute-force for unconverged points: 64 lanes/point, coalesced full sweeps.
// Last block finalizes the loss (k_prep/k_search sums complete by stream order).
__global__ __launch_bounds__(256) void k_slow(const float4* __restrict__ pos,
                                              const float* __restrict__ logp,
                                              float* __restrict__ accum,
                                              const int* __restrict__ queue,
                                              const int* __restrict__ qcount,
                                              unsigned* __restrict__ done,
                                              float* __restrict__ out) {
    const int lane = threadIdx.x & 63;
    const int wid  = (blockIdx.x * 256 + threadIdx.x) >> 6;
    const int nw   = (gridDim.x * 256) >> 6;
    const int qc   = *qcount;
    float sb = 0.f, nb = 0.f;

    for (int q = wid; q < qc; q += nw) {
        const int i = queue[q];
        const float4 me = pos[i];
        const int bits  = __float_as_int(me.w);
        const int labp1 = bits & 31;
        const int orig  = bits >> 5;

        float db2 = 3.0e38f;
        for (int j = lane; j < N_PTS; j += 64) {
            float4 p = pos[j];
            float d2 = dist2f(me.x, me.y, me.z, p.x, p.y, p.z);
            int pl = __float_as_int(p.w) & 31;
            bool diff = (pl != 0) && (pl != labp1);
            db2 = fminf(db2, diff ? d2 : 3.0e38f);
        }
#pragma unroll
        for (int m = 1; m < 64; m <<= 1) db2 = fminf(db2, __shfl_xor(db2, m, 64));

        int cnt = 0;
        for (int j = lane; j < N_PTS; j += 64) {
            float4 p = pos[j];
            float d2 = dist2f(me.x, me.y, me.z, p.x, p.y, p.z);
            cnt += (d2 < db2) ? 1 : 0;
        }
#pragma unroll
        for (int m = 1; m < 64; m <<= 1) cnt += __shfl_xor(cnt, m, 64);

        if (lane == 0) {
            bool bnd = (labp1 != 0) && ((cnt - 1) < KNN);
            if (bnd) { sb += logp[orig]; nb += 1.f; }
        }
    }
    if (lane == 0 && nb > 0.f) {
        atomicAdd(&accum[2], sb);
        atomicAdd(&accum[3], nb);
    }
    __syncthreads();
    if (threadIdx.x == 0) {
        __threadfence();
        if (atomicAdd(done, 1u) == (unsigned)(gridDim.x - 1)) {
            float Sm = atomicAdd(&accum[0], 0.f);
            float Cm = atomicAdd(&accum[1], 0.f);
            float Sb = atomicAdd(&accum[2], 0.f);
            float Cb = atomicAdd(&accum[3], 0.f);
            float main_loss = (Cm > 0.f) ? (-Sm / fmaxf(Cm, 1.f)) : 0.f;
            float bnd_loss  = (Cb > 0.f) ? (-Sb / fmaxf(Cb, 1.f)) : 0.f;
            out[0] = main_loss + BND_W * bnd_loss;
        }
    }
}

extern "C" void kernel_launch(void* const* d_in, const int* in_sizes, int n_in,
                              void* d_out, int out_size, void* d_ws, size_t ws_size,
                              hipStream_t stream) {
    const float* coord  = (const float*)d_in[0];
    const float* logits = (const float*)d_in[1];
    const int*   seg    = (const int*)d_in[2];
    (void)in_sizes; (void)n_in; (void)out_size; (void)ws_size;

    char* w = (char*)d_ws;
    int*      hist      = (int*)(w + 0x00000);      // 32768 i32 (128 KB)
    int*      bin_start = (int*)(w + 0x20000);      // 32769 i32 (int4-aligned)
    int*      cursor    = (int*)(w + 0x60000);      // 32768 i32 (int4-aligned)
    float4*   pos       = (float4*)(w + 0x80000);   // 16384 f32x4 (256 KB)
    float*    logp      = (float*)(w + 0xC0000);    // 16384 f32 (64 KB)
    int*      queue     = (int*)(w + 0xD0000);      // 16384 i32 (64 KB)
    float*    accum     = (float*)(w + 0xE0000);    // 4 f32
    unsigned* done      = (unsigned*)(w + 0xE0010);
    int*      qcount    = (int*)(w + 0xE0020);

    hipMemsetAsync(hist, 0, NBINS * sizeof(int), stream);
    hipMemsetAsync(accum, 0, 0x40, stream);   // accum + done + qcount

    k_prep   <<<N_PTS / 256, 256, 0, stream>>>(coord, seg, logits, hist, logp, accum);
    k_scan   <<<1, 512, 0, stream>>>((const int4*)hist, bin_start, cursor);
    k_scatter<<<N_PTS / 256, 256, 0, stream>>>(coord, seg, cursor, pos);
    k_search <<<N_PTS / 64, 64, 0, stream>>>(pos, bin_start, logp, accum, queue, qcount);
    k_slow   <<<128, 256, 0, stream>>>(pos, logp, accum, queue, qcount, done, (float*)d_out);
}

// Round 15
// 157.697 us; speedup vs baseline: 4.0783x; 1.2468x over previous
//
#include <hip/hip_runtime.h>
#include <math.h>

#define N_PTS 16384
#define KNN   16
#define NCLS  20
#define BND_W 1.0f

#define G       32
#define NBINS   (G * G * G)          // 32768
#define CELL_H  0.28125f             // 9/32, exact in binary
#define H2      0.0791015625f        // (9/32)^2, exact
#define GRID_LO -4.5f
#define INV_H   (32.0f / 9.0f)

#define SUBL    8                    // lanes cooperating per point

// identical distance expression everywhere (forced fmaf -> bit-identical)
__device__ __forceinline__ float dist2f(float ax, float ay, float az,
                                        float bx, float by, float bz) {
    float dx = ax - bx, dy = ay - by, dz = az - bz;
    return __builtin_fmaf(dx, dx, __builtin_fmaf(dy, dy, dz * dz));
}

__device__ __forceinline__ int clampi(int v, int lo, int hi) {
    return min(hi, max(lo, v));
}

__device__ __forceinline__ void cell_xyz(float x, float y, float z,
                                         int& cx, int& cy, int& cz) {
    cx = clampi((int)floorf((x - GRID_LO) * INV_H), 0, G - 1);
    cy = clampi((int)floorf((y - GRID_LO) * INV_H), 0, G - 1);
    cz = clampi((int)floorf((z - GRID_LO) * INV_H), 0, G - 1);
}

__device__ __forceinline__ float waveReduceSum(float v) {
#pragma unroll
    for (int off = 32; off > 0; off >>= 1) v += __shfl_down(v, off, 64);
    return v;
}

// hist + fused main-CE (coalesced logits pass); logp stored for later gather
__global__ __launch_bounds__(256) void k_prep(const float* __restrict__ coord,
                                              const int* __restrict__ seg,
                                              const float* __restrict__ logits,
                                              int* __restrict__ hist,
                                              float* __restrict__ logp,
                                              float* __restrict__ accum) {
    const int i = blockIdx.x * 256 + threadIdx.x;
    int cx, cy, cz;
    cell_xyz(coord[3 * i], coord[3 * i + 1], coord[3 * i + 2], cx, cy, cz);
    atomicAdd(&hist[(cx * G + cy) * G + cz], 1);

    int sg = seg[i];
    bool valid = (sg != -1);
    const float4* row4 = (const float4*)(logits + (size_t)i * NCLS);
    float a[NCLS];
    float4 v0 = row4[0], v1 = row4[1], v2 = row4[2], v3 = row4[3], v4 = row4[4];
    a[0]=v0.x; a[1]=v0.y; a[2]=v0.z; a[3]=v0.w;
    a[4]=v1.x; a[5]=v1.y; a[6]=v1.z; a[7]=v1.w;
    a[8]=v2.x; a[9]=v2.y; a[10]=v2.z; a[11]=v2.w;
    a[12]=v3.x; a[13]=v3.y; a[14]=v3.z; a[15]=v3.w;
    a[16]=v4.x; a[17]=v4.y; a[18]=v4.z; a[19]=v4.w;
    float mx = a[0];
#pragma unroll
    for (int c = 1; c < NCLS; c++) mx = fmaxf(mx, a[c]);
    float se = 0.f;
#pragma unroll
    for (int c = 0; c < NCLS; c++) se += __expf(a[c] - mx);
    int tgt = min(max(sg, 0), NCLS - 1);
    float at = 0.f;
#pragma unroll
    for (int c = 0; c < NCLS; c++) at += (c == tgt) ? a[c] : 0.f;
    float lp = at - mx - __logf(se);
    logp[i] = lp;

    float sm = valid ? lp : 0.f, nm = valid ? 1.f : 0.f;
    sm = waveReduceSum(sm);
    nm = waveReduceSum(nm);
    if ((threadIdx.x & 63) == 0) {
        atomicAdd(&accum[0], sm);
        atomicAdd(&accum[1], nm);
    }
}

// single block; int4-vectorized chunk sums + LDS Hillis-Steele
__global__ __launch_bounds__(512) void k_scan(const int4* __restrict__ h4,
                                              int* __restrict__ bin_start,
                                              int* __restrict__ cursor) {
    __shared__ int part[512];
    const int t = threadIdx.x;
    int4 v[16];
    int s = 0;
#pragma unroll
    for (int k = 0; k < 16; k++) {
        v[k] = h4[t * 16 + k];
        s += v[k].x + v[k].y + v[k].z + v[k].w;
    }
    part[t] = s;
    __syncthreads();
    for (int off = 1; off < 512; off <<= 1) {
        int u = (t >= off) ? part[t - off] : 0;
        __syncthreads();
        part[t] += u;
        __syncthreads();
    }
    int run = part[t] - s;   // exclusive base of this thread's 64-bin chunk
    int4* bs4 = (int4*)bin_start;
    int4* cu4 = (int4*)cursor;
#pragma unroll
    for (int k = 0; k < 16; k++) {
        int4 w;
        w.x = run;
        w.y = w.x + v[k].x;
        w.z = w.y + v[k].y;
        w.w = w.z + v[k].z;
        run = w.w + v[k].w;
        bs4[t * 16 + k] = w;
        cu4[t * 16 + k] = w;
    }
    if (t == 511) bin_start[NBINS] = run;   // == N_PTS
}

// scatter into sorted order; record = (x,y,z, pack(orig<<5 | lab+1))
__global__ __launch_bounds__(256) void k_scatter(const float* __restrict__ coord,
                                                 const int* __restrict__ seg,
                                                 int* __restrict__ cursor,
                                                 float4* __restrict__ pos) {
    const int i = blockIdx.x * 256 + threadIdx.x;
    float x = coord[3 * i], y = coord[3 * i + 1], z = coord[3 * i + 2];
    int cx, cy, cz;
    cell_xyz(x, y, z, cx, cy, cz);
    int idx = atomicAdd(&cursor[(cx * G + cy) * G + cz], 1);
    float4 rec;
    rec.x = x; rec.y = y; rec.z = z;
    rec.w = __int_as_float((i << 5) | ((seg[i] + 1) & 31));
    pos[idx] = rec;
}

// SUBL lanes per sorted point; r=1 cube as 9 register-cached z-runs.
// Converged (db2 <= h^2: cube-1 provably covers min AND count) -> finish here.
// Else push to queue for the brute-force kernel.
__global__ __launch_bounds__(256) void k_search(const float4* __restrict__ pos,
                                                const int* __restrict__ bs,
                                                const float* __restrict__ logp,
                                                float* __restrict__ accum,
                                                int* __restrict__ queue,
                                                int* __restrict__ qcount) {
    const int gid = blockIdx.x * 256 + threadIdx.x;
    const int i   = gid >> 3;        // sorted point id (8 lanes each, consecutive)
    const int sub = gid & (SUBL - 1);
    const float4 me = pos[i];
    const int bits  = __float_as_int(me.w);
    const int labp1 = bits & 31;
    const int orig  = bits >> 5;
    int cx, cy, cz;
    cell_xyz(me.x, me.y, me.z, cx, cy, cz);
    const int zlo = max(0, cz - 1), zhi = min(G - 1, cz + 1);

    int lo[9], hi[9];
#pragma unroll
    for (int dx = 0; dx < 3; dx++)
#pragma unroll
        for (int dy = 0; dy < 3; dy++) {
            const int q = dx * 3 + dy;
            int ix = cx + dx - 1, iy = cy + dy - 1;
            bool ok = (ix >= 0) && (ix < G) && (iy >= 0) && (iy < G);
            int cb = (ix * G + iy) * G;
            lo[q] = ok ? bs[cb + zlo] : 0;
            hi[q] = ok ? bs[cb + zhi + 1] : 0;
        }

    // Phase A over the 27-cell cube (9 z-runs, SUBL-strided)
    float db2 = 3.0e38f;
#pragma unroll
    for (int q = 0; q < 9; q++)
        for (int j = lo[q] + sub; j < hi[q]; j += SUBL) {
            float4 p = pos[j];
            float d2 = dist2f(me.x, me.y, me.z, p.x, p.y, p.z);
            int pl = __float_as_int(p.w) & 31;
            bool diff = (pl != 0) && (pl != labp1);
            db2 = fminf(db2, diff ? d2 : 3.0e38f);
        }
#pragma unroll
    for (int m = 1; m < SUBL; m <<= 1) db2 = fminf(db2, __shfl_xor(db2, m, 64));

    float sb = 0.f, nb = 0.f;
    if (db2 <= H2) {
        // Phase B: count d2 < db2; all qualifying points are inside cube-1
        int cnt = 0;
#pragma unroll
        for (int q = 0; q < 9; q++)
            for (int j = lo[q] + sub; j < hi[q]; j += SUBL) {
                float4 p = pos[j];
                float d2 = dist2f(me.x, me.y, me.z, p.x, p.y, p.z);
                cnt += (d2 < db2) ? 1 : 0;   // self once; argmin excluded (d2==db2)
            }
#pragma unroll
        for (int m = 1; m < SUBL; m <<= 1) cnt += __shfl_xor(cnt, m, 64);
        if (sub == 0) {
            bool bnd = (labp1 != 0) && ((cnt - 1) < KNN);
            if (bnd) { sb = logp[orig]; nb = 1.f; }
        }
    } else if (sub == 0) {
        int qi = atomicAdd(qcount, 1);
        queue[qi] = i;
    }
    sb = waveReduceSum(sb);
    nb = waveReduceSum(nb);
    if ((threadIdx.x & 63) == 0 && nb > 0.f) {
        atomicAdd(&accum[2], sb);
        atomicAdd(&accum[3], nb);
    }
}

// Brute-force for unconverged points: 64 lanes/point, coalesced full sweeps.
// Last block finalizes the loss (k_prep/k_search sums complete by stream order).
__global__ __launch_bounds__(256) void k_slow(const float4* __restrict__ pos,
                                              const float* __restrict__ logp,
                                              float* __restrict__ accum,
                                              const int* __restrict__ queue,
                                              const int* __restrict__ qcount,
                                              unsigned* __restrict__ done,
                                              float* __restrict__ out) {
    const int lane = threadIdx.x & 63;
    const int wid  = (blockIdx.x * 256 + threadIdx.x) >> 6;
    const int nw   = (gridDim.x * 256) >> 6;
    const int qc   = *qcount;
    float sb = 0.f, nb = 0.f;

    for (int q = wid; q < qc; q += nw) {
        const int i = queue[q];
        const float4 me = pos[i];
        const int bits  = __float_as_int(me.w);
        const int labp1 = bits & 31;
        const int orig  = bits >> 5;

        float db2 = 3.0e38f;
        for (int j = lane; j < N_PTS; j += 64) {
            float4 p = pos[j];
            float d2 = dist2f(me.x, me.y, me.z, p.x, p.y, p.z);
            int pl = __float_as_int(p.w) & 31;
            bool diff = (pl != 0) && (pl != labp1);
            db2 = fminf(db2, diff ? d2 : 3.0e38f);
        }
#pragma unroll
        for (int m = 1; m < 64; m <<= 1) db2 = fminf(db2, __shfl_xor(db2, m, 64));

        int cnt = 0;
        for (int j = lane; j < N_PTS; j += 64) {
            float4 p = pos[j];
            float d2 = dist2f(me.x, me.y, me.z, p.x, p.y, p.z);
            cnt += (d2 < db2) ? 1 : 0;
        }
#pragma unroll
        for (int m = 1; m < 64; m <<= 1) cnt += __shfl_xor(cnt, m, 64);

        if (lane == 0) {
            bool bnd = (labp1 != 0) && ((cnt - 1) < KNN);
            if (bnd) { sb += logp[orig]; nb += 1.f; }
        }
    }
    if (lane == 0 && nb > 0.f) {
        atomicAdd(&accum[2], sb);
        atomicAdd(&accum[3], nb);
    }
    __syncthreads();
    if (threadIdx.x == 0) {
        __threadfence();
        if (atomicAdd(done, 1u) == (unsigned)(gridDim.x - 1)) {
            float Sm = atomicAdd(&accum[0], 0.f);
            float Cm = atomicAdd(&accum[1], 0.f);
            float Sb = atomicAdd(&accum[2], 0.f);
            float Cb = atomicAdd(&accum[3], 0.f);
            float main_loss = (Cm > 0.f) ? (-Sm / fmaxf(Cm, 1.f)) : 0.f;
            float bnd_loss  = (Cb > 0.f) ? (-Sb / fmaxf(Cb, 1.f)) : 0.f;
            out[0] = main_loss + BND_W * bnd_loss;
        }
    }
}

extern "C" void kernel_launch(void* const* d_in, const int* in_sizes, int n_in,
                              void* d_out, int out_size, void* d_ws, size_t ws_size,
                              hipStream_t stream) {
    const float* coord  = (const float*)d_in[0];
    const float* logits = (const float*)d_in[1];
    const int*   seg    = (const int*)d_in[2];
    (void)in_sizes; (void)n_in; (void)out_size; (void)ws_size;

    char* w = (char*)d_ws;
    int*      hist      = (int*)(w + 0x00000);      // 32768 i32 (128 KB)
    int*      bin_start = (int*)(w + 0x20000);      // 32769 i32 (int4-aligned)
    int*      cursor    = (int*)(w + 0x60000);      // 32768 i32 (int4-aligned)
    float4*   pos       = (float4*)(w + 0x80000);   // 16384 f32x4 (256 KB)
    float*    logp      = (float*)(w + 0xC0000);    // 16384 f32 (64 KB)
    int*      queue     = (int*)(w + 0xD0000);      // 16384 i32 (64 KB)
    float*    accum     = (float*)(w + 0xE0000);    // 4 f32
    unsigned* done      = (unsigned*)(w + 0xE0010);
    int*      qcount    = (int*)(w + 0xE0020);

    hipMemsetAsync(hist, 0, NBINS * sizeof(int), stream);
    hipMemsetAsync(accum, 0, 0x40, stream);   // accum + done + qcount

    k_prep   <<<N_PTS / 256, 256, 0, stream>>>(coord, seg, logits, hist, logp, accum);
    k_scan   <<<1, 512, 0, stream>>>((const int4*)hist, bin_start, cursor);
    k_scatter<<<N_PTS / 256, 256, 0, stream>>>(coord, seg, cursor, pos);
    k_search <<<(N_PTS * SUBL) / 256, 256, 0, stream>>>(pos, bin_start, logp, accum,
                                                        queue, qcount);
    k_slow   <<<128, 256, 0, stream>>>(pos, logp, accum, queue, qcount, done, (float*)d_out);
}